// Round 1
// baseline (472.320 us; speedup 1.0000x reference)
//
#include <hip/hip_runtime.h>
#include <hip/hip_bf16.h>
#include <stdint.h>

typedef unsigned short u16;
typedef __attribute__((ext_vector_type(8))) short bf16x8;
typedef __attribute__((ext_vector_type(4))) float f32x4;

#define B_DIM 2
#define T_DIM 2048
#define MM_DIM 512
#define S_DIM 3072
#define C_DIM 1024
#define H_DIM 16
#define D_DIM 64

static __device__ __forceinline__ u16 f2b(float f){
  __hip_bfloat16 h = __float2bfloat16(f);
  union { __hip_bfloat16 h; u16 u; } cv; cv.h = h; return cv.u;
}
static __device__ __forceinline__ float b2f(u16 u){
  union { u16 u; __hip_bfloat16 h; } cv; cv.u = u;
  return __bfloat162float(cv.h);
}
static __device__ __forceinline__ void gload_lds16(const void* g, void* lds){
  __builtin_amdgcn_global_load_lds((const __attribute__((address_space(1))) uint32_t*)g,
                                   (__attribute__((address_space(3))) uint32_t*)lds, 16, 0, 0);
}

// ---------- prep: concat + cast x/fm/rm -> kvx (bf16) ----------
__global__ __launch_bounds__(256) void prep_cast_kernel(
    const float* __restrict__ x, const float* __restrict__ fm, const float* __restrict__ rm,
    u16* __restrict__ kvx)
{
  int idx = blockIdx.x*256 + threadIdx.x;      // one 8-element chunk
  long e0 = (long)idx*8;
  int b = (int)(e0 / ((long)S_DIM*C_DIM));
  long r = e0 - (long)b*S_DIM*C_DIM;
  int s  = (int)(r / C_DIM);
  int cc = (int)(r % C_DIM);
  const float* src;
  if (s < T_DIM)              src = x  + ((long)b*T_DIM + s)*C_DIM + cc;
  else if (s < T_DIM+MM_DIM)  src = fm + ((long)b*MM_DIM + (s-T_DIM))*C_DIM + cc;
  else                        src = rm + ((long)b*MM_DIM + (s-T_DIM-MM_DIM))*C_DIM + cc;
  f32x4 a  = *(const f32x4*)src;
  f32x4 b4 = *(const f32x4*)(src+4);
  bf16x8 o;
  o[0]=(short)f2b(a[0]);  o[1]=(short)f2b(a[1]);  o[2]=(short)f2b(a[2]);  o[3]=(short)f2b(a[3]);
  o[4]=(short)f2b(b4[0]); o[5]=(short)f2b(b4[1]); o[6]=(short)f2b(b4[2]); o[7]=(short)f2b(b4[3]);
  *(bf16x8*)(kvx + e0) = o;
}

// ---------- weight transpose + cast: WT[n][k] = W[k][n] (bf16) ----------
__global__ __launch_bounds__(256) void transpose_w_kernel(
    const float* __restrict__ W, u16* __restrict__ WT)
{
  int idx = blockIdx.x*256 + threadIdx.x;  // C*C/8 chunks
  int n  = idx >> 7;
  int k0 = (idx & 127) * 8;
  bf16x8 o;
  #pragma unroll
  for (int j=0;j<8;j++) o[j] = (short)f2b(W[(long)(k0+j)*C_DIM + n]);
  *(bf16x8*)(WT + (long)n*C_DIM + k0) = o;
}

// ---------- bf16 GEMM: C[m][n] = sum_k A[m][k] * Bt[n][k] ----------
// 128x128 tile, BK=64, 4 waves (2x2), m97-style global_load_lds staging.
// A row m maps to physical row (m/RA)*SBrows + m%RA (row stride = K elements).
__global__ __launch_bounds__(256) void gemm_bt_kernel(
    const u16* __restrict__ A, const u16* __restrict__ Bt,
    u16* __restrict__ Cbf, float* __restrict__ Cf,
    int N, int K, int RA, int SBrows)
{
  __shared__ u16 As[128*64];
  __shared__ u16 Bs[128*64];
  const int tid = threadIdx.x;
  const int w = tid>>6, lane = tid&63, g = lane>>4, c = lane&15;
  const int bx = blockIdx.x, by = blockIdx.y;
  const int wm = (w>>1)*64, wn = (w&1)*64;
  const f32x4 ZERO = {0.f,0.f,0.f,0.f};
  f32x4 acc[4][4];
  #pragma unroll
  for (int m=0;m<4;m++)
    #pragma unroll
    for (int n=0;n<4;n++) acc[m][n] = ZERO;

  const int srow = lane>>3;       // 0..7
  const int scol = (lane&7)*8;    // element col in tile

  for (int ks=0; ks<K; ks+=64){
    #pragma unroll
    for (int i=0;i<4;i++){
      int ci  = w*4 + i;          // 1KB chunk, rows ci*8..+7
      int row = ci*8 + srow;
      int gr  = by*128 + row;
      long mr = (long)(gr/RA)*SBrows + (gr%RA);
      gload_lds16(A + mr*(long)K + ks + scol, (void*)(As + ci*512));
      long gn = (long)bx*128 + row;
      gload_lds16(Bt + gn*(long)K + ks + scol, (void*)(Bs + ci*512));
    }
    __syncthreads();
    #pragma unroll
    for (int kk=0;kk<2;kk++){
      bf16x8 af[4], bfv[4];
      #pragma unroll
      for (int m=0;m<4;m++) af[m]  = *(const bf16x8*)(As + (wm + m*16 + c)*64 + kk*32 + g*8);
      #pragma unroll
      for (int n=0;n<4;n++) bfv[n] = *(const bf16x8*)(Bs + (wn + n*16 + c)*64 + kk*32 + g*8);
      #pragma unroll
      for (int m=0;m<4;m++)
        #pragma unroll
        for (int n=0;n<4;n++)
          acc[m][n] = __builtin_amdgcn_mfma_f32_16x16x32_bf16(af[m], bfv[n], acc[m][n], 0,0,0);
    }
    __syncthreads();
  }
  // epilogue: C-layout col=lane&15, row=(lane>>4)*4+reg
  #pragma unroll
  for (int m=0;m<4;m++)
    #pragma unroll
    for (int n=0;n<4;n++){
      int row0 = by*128 + wm + m*16 + 4*g;
      int col  = bx*128 + wn + n*16 + c;
      #pragma unroll
      for (int r=0;r<4;r++){
        float v = acc[m][n][r];
        long off = (long)(row0 + r)*N + col;
        if (Cbf) Cbf[off] = f2b(v);
        else     Cf[off]  = v;
      }
    }
}

// ---------- gate: g = sigmoid(q @ gate_W + gate_b), partial sums for loss ----------
__global__ __launch_bounds__(256) void gate_kernel(
    const u16* __restrict__ Qb, const float* __restrict__ gW, const float* __restrict__ gb,
    float* __restrict__ Gate, float* __restrict__ Part)
{
  __shared__ float qrow[4][1024];
  const int tid = threadIdx.x, w = tid>>6, lane = tid&63;
  const int m = blockIdx.x*4 + w;
  #pragma unroll
  for (int i=0;i<16;i++)
    qrow[w][lane + 64*i] = b2f(Qb[(long)m*C_DIM + lane + 64*i]);
  asm volatile("s_waitcnt lgkmcnt(0)" ::: "memory");
  const int h = lane & 15, sl = lane >> 4;
  float acc = 0.f;
  #pragma unroll 8
  for (int i=0;i<256;i++){
    int cc = sl*256 + i;
    acc += qrow[w][cc] * gW[(long)cc*H_DIM + h];
  }
  acc += __shfl_xor(acc, 16, 64);
  acc += __shfl_xor(acc, 32, 64);
  float gv = 1.0f/(1.0f + __expf(-(acc + gb[h])));
  float p = gv;
  p += __shfl_xor(p,1,64); p += __shfl_xor(p,2,64);
  p += __shfl_xor(p,4,64); p += __shfl_xor(p,8,64);
  if (lane < 16) Gate[(long)m*H_DIM + lane] = gv;
  if (lane == 0) Part[m] = p;
}

// ---------- loss: 0.01 * mean(g) ----------
__global__ __launch_bounds__(256) void loss_kernel(const float* __restrict__ Part, float* __restrict__ out)
{
  int tid = threadIdx.x;
  float s = 0.f;
  for (int i=tid; i<B_DIM*T_DIM; i+=256) s += Part[i];
  #pragma unroll
  for (int m=1;m<64;m<<=1) s += __shfl_xor(s,m,64);
  __shared__ float red[4];
  if ((tid&63)==0) red[tid>>6] = s;
  __syncthreads();
  if (tid==0)
    out[(long)B_DIM*T_DIM*C_DIM] = 0.01f*(red[0]+red[1]+red[2]+red[3])/(float)(B_DIM*T_DIM*H_DIM);
}

// ---------- fused attention: per (b,h,64-query tile); wave = 16 query rows ----------
__global__ __launch_bounds__(256) void attn_kernel(
    const u16* __restrict__ Qb, const u16* __restrict__ Kb, const u16* __restrict__ Vb,
    const float* __restrict__ Gate, u16* __restrict__ Yb)
{
  __shared__ u16 Ks[64*64];       // [key][d], XOR-swizzled cols by 8*(key&7)
  __shared__ u16 Vt[64*64];       // [d][key], XOR-swizzled cols by 8*(d&7)
  __shared__ u16 Ps[4][16*64];    // per-wave P[q][key], swizzled by 8*(q&7)
  const int tid = threadIdx.x;
  const int w = tid>>6, lane = tid&63, g = lane>>4, c = lane&15;
  const int bid = blockIdx.x;
  const int qt = bid & 31, h = (bid>>5)&15, b = bid>>9;
  const int qrow_w = qt*64 + w*16;
  const long qgrow = (long)b*T_DIM + qrow_w + c;   // this lane's query row (A-frag row / PV col)
  const f32x4 ZERO = {0.f,0.f,0.f,0.f};

  bf16x8 qf0 = *(const bf16x8*)(Qb + qgrow*C_DIM + h*D_DIM + g*8);
  bf16x8 qf1 = *(const bf16x8*)(Qb + qgrow*C_DIM + h*D_DIM + 32 + g*8);

  f32x4 accA[4], accB[4];           // Yt-layout: col=q(lane&15), row=d(4g+reg), dn = d/16
  #pragma unroll
  for (int dn=0;dn<4;dn++){ accA[dn]=ZERO; accB[dn]=ZERO; }
  float m_r[4] = {-1e30f,-1e30f,-1e30f,-1e30f};
  float l_r[4] = {0.f,0.f,0.f,0.f};

  const int nLocal = qt + 1;
  const int nTot   = nLocal + (2*MM_DIM)/64;

  for (int blk=0; blk<nTot; blk++){
    const int isMem = (blk >= nLocal);
    const int key0  = isMem ? (T_DIM + (blk-nLocal)*64) : blk*64;
    __syncthreads();   // previous tile fully consumed
    // stage K: linear LDS dest, pre-swizzled global source (rule #21)
    #pragma unroll
    for (int i=0;i<2;i++){
      int ci  = w*2 + i;
      int row = ci*8 + (lane>>3);
      int col = 8*((lane&7) ^ (row&7));
      gload_lds16(Kb + ((long)b*S_DIM + key0 + row)*C_DIM + h*D_DIM + col, (void*)(Ks + ci*512));
    }
    // stage V transposed (reg-staged), swizzled writes (conflict-free: key=lane)
    #pragma unroll
    for (int r2=0;r2<2;r2++){
      int d0 = 8*(w + 4*r2);
      bf16x8 vv = *(const bf16x8*)(Vb + ((long)b*S_DIM + key0 + lane)*C_DIM + h*D_DIM + d0);
      #pragma unroll
      for (int j=0;j<8;j++){
        int d = d0 + j;
        Vt[d*64 + (lane ^ (8*(d&7)))] = (u16)vv[j];
      }
    }
    __syncthreads();
    // ---- QK^T: scores[q=4g+reg][key=c+16n] ----
    f32x4 s[4];
    #pragma unroll
    for (int n=0;n<4;n++) s[n] = ZERO;
    #pragma unroll
    for (int n=0;n<4;n++){
      int key = c + 16*n;
      #pragma unroll
      for (int kk=0;kk<2;kk++){
        bf16x8 kf = *(const bf16x8*)(Ks + key*64 + ((kk*32 + 8*g) ^ (8*(key&7))));
        bf16x8 qk = (kk==0) ? qf0 : qf1;
        s[n] = __builtin_amdgcn_mfma_f32_16x16x32_bf16(qk, kf, s[n], 0,0,0);
      }
    }
    // scale + causal mask (local keys only)
    #pragma unroll
    for (int n=0;n<4;n++){
      #pragma unroll
      for (int r=0;r<4;r++){
        float sv = s[n][r]*0.125f;
        if (!isMem){
          int key = key0 + 16*n + c;
          int q   = qrow_w + 4*g + r;
          if (key > q) sv = -1e30f;
        }
        s[n][r] = sv;
      }
    }
    // ---- online softmax (row stats per reg; keys spread over 16 lanes) ----
    float alpha[4];
    #pragma unroll
    for (int r=0;r<4;r++){
      float rmx = fmaxf(fmaxf(s[0][r],s[1][r]), fmaxf(s[2][r],s[3][r]));
      rmx = fmaxf(rmx, __shfl_xor(rmx,1,64));
      rmx = fmaxf(rmx, __shfl_xor(rmx,2,64));
      rmx = fmaxf(rmx, __shfl_xor(rmx,4,64));
      rmx = fmaxf(rmx, __shfl_xor(rmx,8,64));
      float mn = fmaxf(m_r[r], rmx);
      alpha[r] = __expf(m_r[r] - mn);
      m_r[r] = mn;
      float t0 = __expf(s[0][r]-mn), t1 = __expf(s[1][r]-mn);
      float t2 = __expf(s[2][r]-mn), t3 = __expf(s[3][r]-mn);
      s[0][r]=t0; s[1][r]=t1; s[2][r]=t2; s[3][r]=t3;
      float rs = t0+t1+t2+t3;
      rs += __shfl_xor(rs,1,64); rs += __shfl_xor(rs,2,64);
      rs += __shfl_xor(rs,4,64); rs += __shfl_xor(rs,8,64);
      l_r[r] = l_r[r]*alpha[r] + rs;
    }
    // redistribute alpha to PV layout (q = lane&15) and rescale accumulators
    {
      int srcl = (c>>2)<<4;
      float a0=__shfl(alpha[0],srcl,64), a1=__shfl(alpha[1],srcl,64);
      float a2=__shfl(alpha[2],srcl,64), a3=__shfl(alpha[3],srcl,64);
      int r3 = c&3;
      float aq = (r3==0)?a0:(r3==1)?a1:(r3==2)?a2:a3;
      #pragma unroll
      for (int dn=0;dn<4;dn++){ accA[dn] *= aq; accB[dn] *= aq; }
    }
    // ---- P -> per-wave LDS (bf16, swizzled) ----
    #pragma unroll
    for (int n=0;n<4;n++){
      #pragma unroll
      for (int r=0;r<4;r++){
        int q = 4*g + r;
        Ps[w][q*64 + ((c + 16*n) ^ (8*(q&7)))] = f2b(s[n][r]);
      }
    }
    asm volatile("s_waitcnt lgkmcnt(0)" ::: "memory");
    // ---- PV (swapped): Yt[d][q] += sum_key Vt[d][key] * P[q][key] ----
    bf16x8 pf0 = *(const bf16x8*)(&Ps[w][c*64 + (( 0 + 8*g) ^ (8*(c&7)))]);
    bf16x8 pf1 = *(const bf16x8*)(&Ps[w][c*64 + ((32 + 8*g) ^ (8*(c&7)))]);
    #pragma unroll
    for (int kk=0;kk<2;kk++){
      bf16x8 pf = (kk==0)?pf0:pf1;
      #pragma unroll
      for (int dn=0;dn<4;dn++){
        int d = dn*16 + c;
        bf16x8 vf = *(const bf16x8*)(&Vt[d*64 + ((kk*32 + 8*g) ^ (8*(c&7)))]);
        if (!isMem) accA[dn] = __builtin_amdgcn_mfma_f32_16x16x32_bf16(vf, pf, accA[dn], 0,0,0);
        else        accB[dn] = __builtin_amdgcn_mfma_f32_16x16x32_bf16(vf, pf, accB[dn], 0,0,0);
      }
    }
  }
  // ---- finalize: Y = (accA + g*accB)/l ----
  int srcl = (c>>2)<<4;
  float l0=__shfl(l_r[0],srcl,64), l1=__shfl(l_r[1],srcl,64);
  float l2=__shfl(l_r[2],srcl,64), l3=__shfl(l_r[3],srcl,64);
  int r3 = c&3;
  float lq = (r3==0)?l0:(r3==1)?l1:(r3==2)?l2:l3;
  float inv = 1.0f/lq;
  float gq = Gate[qgrow*H_DIM + h];
  #pragma unroll
  for (int dn=0;dn<4;dn++){
    #pragma unroll
    for (int r=0;r<4;r++){
      float v = (accA[dn][r] + gq*accB[dn][r])*inv;
      int d = dn*16 + 4*g + r;
      Yb[qgrow*C_DIM + h*D_DIM + d] = f2b(v);
    }
  }
}

extern "C" void kernel_launch(void* const* d_in, const int* in_sizes, int n_in,
                              void* d_out, int out_size, void* d_ws, size_t ws_size,
                              hipStream_t stream)
{
  (void)in_sizes; (void)n_in; (void)out_size;
  const float* x  = (const float*)d_in[0];
  const float* fm = (const float*)d_in[1];
  const float* rm = (const float*)d_in[2];
  const float* Wq = (const float*)d_in[3];
  const float* Wk = (const float*)d_in[4];
  const float* Wv = (const float*)d_in[5];
  const float* Wo = (const float*)d_in[6];
  const float* gW = (const float*)d_in[7];
  const float* gb = (const float*)d_in[8];
  float* out = (float*)d_out;

  char* p = (char*)d_ws;
  u16* kvx = (u16*)p;  p += (long)B_DIM*S_DIM*C_DIM*2;
  u16* qb  = (u16*)p;  p += (long)B_DIM*T_DIM*C_DIM*2;
  u16* kb  = (u16*)p;  p += (long)B_DIM*S_DIM*C_DIM*2;
  u16* vb  = (u16*)p;  p += (long)B_DIM*S_DIM*C_DIM*2;
  u16* yb  = (u16*)p;  p += (long)B_DIM*T_DIM*C_DIM*2;
  u16* WqT = (u16*)p;  p += (long)C_DIM*C_DIM*2;
  u16* WkT = (u16*)p;  p += (long)C_DIM*C_DIM*2;
  u16* WvT = (u16*)p;  p += (long)C_DIM*C_DIM*2;
  u16* WoT = (u16*)p;  p += (long)C_DIM*C_DIM*2;
  float* Gate = (float*)p; p += (long)B_DIM*T_DIM*H_DIM*4;
  float* Part = (float*)p; p += (long)B_DIM*T_DIM*4;
  if ((size_t)(p - (char*)d_ws) > ws_size) return;   // workspace too small

  prep_cast_kernel<<<(B_DIM*S_DIM*C_DIM/8)/256, 256, 0, stream>>>(x, fm, rm, kvx);
  transpose_w_kernel<<<(C_DIM*C_DIM/8)/256, 256, 0, stream>>>(Wq, WqT);
  transpose_w_kernel<<<(C_DIM*C_DIM/8)/256, 256, 0, stream>>>(Wk, WkT);
  transpose_w_kernel<<<(C_DIM*C_DIM/8)/256, 256, 0, stream>>>(Wv, WvT);
  transpose_w_kernel<<<(C_DIM*C_DIM/8)/256, 256, 0, stream>>>(Wo, WoT);

  // q = x@Wq  (A rows are the x-region of kvx: RA=T, batch stride S rows)
  gemm_bt_kernel<<<dim3(8, (B_DIM*T_DIM)/128), 256, 0, stream>>>(kvx, WqT, qb, nullptr,
      C_DIM, C_DIM, T_DIM, S_DIM);
  // k,v = kvx@Wk / kvx@Wv (contiguous rows)
  gemm_bt_kernel<<<dim3(8, (B_DIM*S_DIM)/128), 256, 0, stream>>>(kvx, WkT, kb, nullptr,
      C_DIM, C_DIM, B_DIM*S_DIM, B_DIM*S_DIM);
  gemm_bt_kernel<<<dim3(8, (B_DIM*S_DIM)/128), 256, 0, stream>>>(kvx, WvT, vb, nullptr,
      C_DIM, C_DIM, B_DIM*S_DIM, B_DIM*S_DIM);

  gate_kernel<<<(B_DIM*T_DIM)/4, 256, 0, stream>>>(qb, gW, gb, Gate, Part);
  loss_kernel<<<1, 256, 0, stream>>>(Part, out);

  attn_kernel<<<B_DIM*H_DIM*(T_DIM/64), 256, 0, stream>>>(qb, kb, vb, Gate, yb);

  // out = Y@Wo (f32 into d_out)
  gemm_bt_kernel<<<dim3(8, (B_DIM*T_DIM)/128), 256, 0, stream>>>(yb, WoT, nullptr, out,
      C_DIM, C_DIM, B_DIM*T_DIM, B_DIM*T_DIM);
}

// Round 2
// 353.480 us; speedup vs baseline: 1.3362x; 1.3362x over previous
//
#include <hip/hip_runtime.h>
#include <hip/hip_bf16.h>
#include <stdint.h>

typedef unsigned short u16;
typedef __attribute__((ext_vector_type(8))) short bf16x8;
typedef __attribute__((ext_vector_type(4))) short s16x4;
typedef __attribute__((ext_vector_type(4))) float f32x4;

#define B_DIM 2
#define T_DIM 2048
#define MM_DIM 512
#define S_DIM 3072
#define C_DIM 1024
#define H_DIM 16
#define D_DIM 64
#define KV_STRIDE 2048

static __device__ __forceinline__ u16 f2b(float f){
  __hip_bfloat16 h = __float2bfloat16(f);
  union { __hip_bfloat16 h; u16 u; } cv; cv.h = h; return cv.u;
}
static __device__ __forceinline__ float b2f(u16 u){
  union { u16 u; __hip_bfloat16 h; } cv; cv.u = u;
  return __bfloat162float(cv.h);
}
static __device__ __forceinline__ void gload_lds16(const void* g, void* lds){
  __builtin_amdgcn_global_load_lds((const __attribute__((address_space(1))) uint32_t*)g,
                                   (__attribute__((address_space(3))) uint32_t*)lds, 16, 0, 0);
}

// ---------- prep: concat + cast x/fm/rm -> kvx (bf16) ----------
__global__ __launch_bounds__(256) void prep_cast_kernel(
    const float* __restrict__ x, const float* __restrict__ fm, const float* __restrict__ rm,
    u16* __restrict__ kvx)
{
  int idx = blockIdx.x*256 + threadIdx.x;      // one 8-element chunk
  long e0 = (long)idx*8;
  int b = (int)(e0 / ((long)S_DIM*C_DIM));
  long r = e0 - (long)b*S_DIM*C_DIM;
  int s  = (int)(r / C_DIM);
  int cc = (int)(r % C_DIM);
  const float* src;
  if (s < T_DIM)              src = x  + ((long)b*T_DIM + s)*C_DIM + cc;
  else if (s < T_DIM+MM_DIM)  src = fm + ((long)b*MM_DIM + (s-T_DIM))*C_DIM + cc;
  else                        src = rm + ((long)b*MM_DIM + (s-T_DIM-MM_DIM))*C_DIM + cc;
  f32x4 a  = *(const f32x4*)src;
  f32x4 b4 = *(const f32x4*)(src+4);
  bf16x8 o;
  o[0]=(short)f2b(a[0]);  o[1]=(short)f2b(a[1]);  o[2]=(short)f2b(a[2]);  o[3]=(short)f2b(a[3]);
  o[4]=(short)f2b(b4[0]); o[5]=(short)f2b(b4[1]); o[6]=(short)f2b(b4[2]); o[7]=(short)f2b(b4[3]);
  *(bf16x8*)(kvx + e0) = o;
}

// ---------- weight transpose + cast: WT[n][k] = W[k][n] (bf16) ----------
__global__ __launch_bounds__(256) void transpose_w_kernel(
    const float* __restrict__ W, u16* __restrict__ WT)
{
  int idx = blockIdx.x*256 + threadIdx.x;  // C*C/8 chunks
  int n  = idx >> 7;
  int k0 = (idx & 127) * 8;
  bf16x8 o;
  #pragma unroll
  for (int j=0;j<8;j++) o[j] = (short)f2b(W[(long)(k0+j)*C_DIM + n]);
  *(bf16x8*)(WT + (long)n*C_DIM + k0) = o;
}

// ---------- bf16 GEMM: C[m][n] = sum_k A[m][k] * Bt[n][k] ----------
__global__ __launch_bounds__(256) void gemm_bt_kernel(
    const u16* __restrict__ A, const u16* __restrict__ Bt,
    u16* __restrict__ Cbf, float* __restrict__ Cf,
    int N, int K, int RA, int SBrows)
{
  __shared__ u16 As[128*64];
  __shared__ u16 Bs[128*64];
  const int tid = threadIdx.x;
  const int w = tid>>6, lane = tid&63, g = lane>>4, c = lane&15;
  const int bx = blockIdx.x, by = blockIdx.y;
  const int wm = (w>>1)*64, wn = (w&1)*64;
  const f32x4 ZERO = {0.f,0.f,0.f,0.f};
  f32x4 acc[4][4];
  #pragma unroll
  for (int m=0;m<4;m++)
    #pragma unroll
    for (int n=0;n<4;n++) acc[m][n] = ZERO;

  const int srow = lane>>3;
  const int scol = (lane&7)*8;

  for (int ks=0; ks<K; ks+=64){
    #pragma unroll
    for (int i=0;i<4;i++){
      int ci  = w*4 + i;
      int row = ci*8 + srow;
      int gr  = by*128 + row;
      long mr = (long)(gr/RA)*SBrows + (gr%RA);
      gload_lds16(A + mr*(long)K + ks + scol, (void*)(As + ci*512));
      long gn = (long)bx*128 + row;
      gload_lds16(Bt + gn*(long)K + ks + scol, (void*)(Bs + ci*512));
    }
    __syncthreads();
    #pragma unroll
    for (int kk=0;kk<2;kk++){
      bf16x8 af[4], bfv[4];
      #pragma unroll
      for (int m=0;m<4;m++) af[m]  = *(const bf16x8*)(As + (wm + m*16 + c)*64 + kk*32 + g*8);
      #pragma unroll
      for (int n=0;n<4;n++) bfv[n] = *(const bf16x8*)(Bs + (wn + n*16 + c)*64 + kk*32 + g*8);
      #pragma unroll
      for (int m=0;m<4;m++)
        #pragma unroll
        for (int n=0;n<4;n++)
          acc[m][n] = __builtin_amdgcn_mfma_f32_16x16x32_bf16(af[m], bfv[n], acc[m][n], 0,0,0);
    }
    __syncthreads();
  }
  #pragma unroll
  for (int m=0;m<4;m++)
    #pragma unroll
    for (int n=0;n<4;n++){
      int row0 = by*128 + wm + m*16 + 4*g;
      int col  = bx*128 + wn + n*16 + c;
      #pragma unroll
      for (int r=0;r<4;r++){
        float v = acc[m][n][r];
        long off = (long)(row0 + r)*N + col;
        if (Cbf) Cbf[off] = f2b(v);
        else     Cf[off]  = v;
      }
    }
}

// ---------- gate ----------
__global__ __launch_bounds__(256) void gate_kernel(
    const u16* __restrict__ Qb, const float* __restrict__ gW, const float* __restrict__ gb,
    float* __restrict__ Gate, float* __restrict__ Part)
{
  __shared__ float qrow[4][1024];
  const int tid = threadIdx.x, w = tid>>6, lane = tid&63;
  const int m = blockIdx.x*4 + w;
  #pragma unroll
  for (int i=0;i<16;i++)
    qrow[w][lane + 64*i] = b2f(Qb[(long)m*C_DIM + lane + 64*i]);
  asm volatile("s_waitcnt lgkmcnt(0)" ::: "memory");
  const int h = lane & 15, sl = lane >> 4;
  float acc = 0.f;
  #pragma unroll 8
  for (int i=0;i<256;i++){
    int cc = sl*256 + i;
    acc += qrow[w][cc] * gW[(long)cc*H_DIM + h];
  }
  acc += __shfl_xor(acc, 16, 64);
  acc += __shfl_xor(acc, 32, 64);
  float gv = 1.0f/(1.0f + __expf(-(acc + gb[h])));
  float p = gv;
  p += __shfl_xor(p,1,64); p += __shfl_xor(p,2,64);
  p += __shfl_xor(p,4,64); p += __shfl_xor(p,8,64);
  if (lane < 16) Gate[(long)m*H_DIM + lane] = gv;
  if (lane == 0) Part[m] = p;
}

// ---------- loss ----------
__global__ __launch_bounds__(256) void loss_kernel(const float* __restrict__ Part, float* __restrict__ out)
{
  int tid = threadIdx.x;
  float s = 0.f;
  for (int i=tid; i<B_DIM*T_DIM; i+=256) s += Part[i];
  #pragma unroll
  for (int m=1;m<64;m<<=1) s += __shfl_xor(s,m,64);
  __shared__ float red[4];
  if ((tid&63)==0) red[tid>>6] = s;
  __syncthreads();
  if (tid==0)
    out[(long)B_DIM*T_DIM*C_DIM] = 0.01f*(red[0]+red[1]+red[2]+red[3])/(float)(B_DIM*T_DIM*H_DIM);
}

// ---------- fused attention (swapped-QK^T, double-buffered, 1 barrier/tile) ----------
__global__ __launch_bounds__(256) void attn_kernel(
    const u16* __restrict__ Qb, const u16* __restrict__ KVb,
    const float* __restrict__ Gate, u16* __restrict__ Yb)
{
  __shared__ u16 Ks[2][64*64];    // [key][d], phys col = d ^ 8*(key&7)
  __shared__ u16 Vt[2][64*64];    // [d][key], phys col = key ^ 8*(d&7)
  __shared__ u16 Ps[4][16*64];    // per-wave P[q][key], phys col = key ^ 8*(q&7)
  const int tid = threadIdx.x;
  const int w = tid>>6, lane = tid&63, g = lane>>4, c = lane&15;
  const int bid = blockIdx.x;
  const int qt = 31 - (bid & 31), h = (bid>>5)&15, b = bid>>9;  // heavy blocks first
  const int qrow_w = qt*64 + w*16;
  const int q_lane = qrow_w + c;
  const long qgrow = (long)b*T_DIM + q_lane;
  const f32x4 ZERO = {0.f,0.f,0.f,0.f};
  const float SC2 = 0.18033688011112042f;   // log2(e)/sqrt(64)

  const u16* Kbase = KVb + (long)b*S_DIM*KV_STRIDE + h*D_DIM;
  const u16* Vbase = Kbase + C_DIM;

  bf16x8 qf0 = *(const bf16x8*)(Qb + qgrow*C_DIM + h*D_DIM + g*8);
  bf16x8 qf1 = *(const bf16x8*)(Qb + qgrow*C_DIM + h*D_DIM + 32 + g*8);

  f32x4 accA[4], accB[4];       // col = q = c, row = d = dn*16 + 4g + r
  #pragma unroll
  for (int dn=0;dn<4;dn++){ accA[dn]=ZERO; accB[dn]=ZERO; }
  float m_r = -1e30f, l_r = 0.f;

  const int nLocal = qt + 1;
  const int nTot   = nLocal + (2*MM_DIM)/64;

  const int srow  = lane>>3;
  const int scolK = 8*((lane&7) ^ srow);   // pre-swizzled global source col
  const int sw    = 8*(c&15 & 7);          // 8*(c&7)

  // prologue: stage tile 0
  {
    #pragma unroll
    for (int i=0;i<2;i++){
      int ci = w*2 + i;
      gload_lds16(Kbase + (long)(ci*8 + srow)*KV_STRIDE + scolK, (void*)(&Ks[0][ci*512]));
    }
    bf16x8 v0 = *(const bf16x8*)(Vbase + (long)lane*KV_STRIDE + 8*w);
    bf16x8 v1 = *(const bf16x8*)(Vbase + (long)lane*KV_STRIDE + 32 + 8*w);
    asm volatile("s_waitcnt vmcnt(0)" ::: "memory");
    #pragma unroll
    for (int j=0;j<8;j++){
      Vt[0][(8*w+j)*64      + (lane ^ (8*j))] = (u16)v0[j];
      Vt[0][(32+8*w+j)*64   + (lane ^ (8*j))] = (u16)v1[j];
    }
  }
  __syncthreads();

  int cur = 0;
  bf16x8 v0, v1;
  for (int blk=0; blk<nTot; blk++){
    const int  isMem = (blk >= nLocal);
    const bool last  = (blk+1 == nTot);
    const int  key0  = isMem ? (T_DIM + (blk-nLocal)*64) : blk*64;
    if (!last){
      int nb = blk+1;
      int nk = (nb >= nLocal) ? (T_DIM + (nb-nLocal)*64) : nb*64;
      #pragma unroll
      for (int i=0;i<2;i++){
        int ci = w*2 + i;
        gload_lds16(Kbase + (long)(nk + ci*8 + srow)*KV_STRIDE + scolK, (void*)(&Ks[cur^1][ci*512]));
      }
      v0 = *(const bf16x8*)(Vbase + (long)(nk+lane)*KV_STRIDE + 8*w);
      v1 = *(const bf16x8*)(Vbase + (long)(nk+lane)*KV_STRIDE + 32 + 8*w);
    }

    // ---- QK^T swapped: s[n][r] = score[key=key0+16n+4g+r][q=q_lane] ----
    f32x4 s[4];
    #pragma unroll
    for (int n=0;n<4;n++) s[n] = ZERO;
    #pragma unroll
    for (int n=0;n<4;n++){
      const u16* kb2 = &Ks[cur][(c + 16*n)*64];
      bf16x8 kf0 = *(const bf16x8*)(kb2 + ((8*g) ^ sw));
      bf16x8 kf1 = *(const bf16x8*)(kb2 + ((32+8*g) ^ sw));
      s[n] = __builtin_amdgcn_mfma_f32_16x16x32_bf16(kf0, qf0, s[n], 0,0,0);
      s[n] = __builtin_amdgcn_mfma_f32_16x16x32_bf16(kf1, qf1, s[n], 0,0,0);
    }
    // scale (exp2 domain) + causal mask (only last local tile straddles)
    #pragma unroll
    for (int n=0;n<4;n++)
      #pragma unroll
      for (int r=0;r<4;r++) s[n][r] *= SC2;
    if (blk == qt){
      #pragma unroll
      for (int n=0;n<4;n++)
        #pragma unroll
        for (int r=0;r<4;r++)
          if (key0 + 16*n + 4*g + r > q_lane) s[n][r] = -1e30f;
    }
    // ---- online softmax: per-lane stats for q=c ----
    float rmx = s[0][0];
    #pragma unroll
    for (int n=0;n<4;n++)
      #pragma unroll
      for (int r=0;r<4;r++) rmx = fmaxf(rmx, s[n][r]);
    rmx = fmaxf(rmx, __shfl_xor(rmx,16,64));
    rmx = fmaxf(rmx, __shfl_xor(rmx,32,64));
    float mn = fmaxf(m_r, rmx);
    float alpha = __builtin_amdgcn_exp2f(m_r - mn);
    m_r = mn;
    float rs = 0.f;
    #pragma unroll
    for (int n=0;n<4;n++)
      #pragma unroll
      for (int r=0;r<4;r++){
        float t = __builtin_amdgcn_exp2f(s[n][r] - mn);
        s[n][r] = t; rs += t;
      }
    rs += __shfl_xor(rs,16,64);
    rs += __shfl_xor(rs,32,64);
    l_r = l_r*alpha + rs;
    #pragma unroll
    for (int dn=0;dn<4;dn++)
      #pragma unroll
      for (int r=0;r<4;r++){ accA[dn][r] *= alpha; accB[dn][r] *= alpha; }

    // ---- P -> per-wave LDS (packed b64 writes) ----
    #pragma unroll
    for (int n=0;n<4;n++){
      s16x4 pk;
      pk[0]=(short)f2b(s[n][0]); pk[1]=(short)f2b(s[n][1]);
      pk[2]=(short)f2b(s[n][2]); pk[3]=(short)f2b(s[n][3]);
      *(s16x4*)(&Ps[w][c*64 + ((16*n + 4*g) ^ sw)]) = pk;
    }
    asm volatile("s_waitcnt lgkmcnt(0)" ::: "memory");
    bf16x8 pf0 = *(const bf16x8*)(&Ps[w][c*64 + ((8*g)    ^ sw)]);
    bf16x8 pf1 = *(const bf16x8*)(&Ps[w][c*64 + ((32+8*g) ^ sw)]);
    // ---- PV: Yt[d][q] += Vt[d][key] * P[q][key] ----
    #pragma unroll
    for (int dn=0;dn<4;dn++){
      const u16* vb2 = &Vt[cur][(dn*16 + c)*64];
      bf16x8 vf0 = *(const bf16x8*)(vb2 + ((8*g)    ^ sw));
      bf16x8 vf1 = *(const bf16x8*)(vb2 + ((32+8*g) ^ sw));
      if (!isMem){
        accA[dn] = __builtin_amdgcn_mfma_f32_16x16x32_bf16(vf0, pf0, accA[dn], 0,0,0);
        accA[dn] = __builtin_amdgcn_mfma_f32_16x16x32_bf16(vf1, pf1, accA[dn], 0,0,0);
      } else {
        accB[dn] = __builtin_amdgcn_mfma_f32_16x16x32_bf16(vf0, pf0, accB[dn], 0,0,0);
        accB[dn] = __builtin_amdgcn_mfma_f32_16x16x32_bf16(vf1, pf1, accB[dn], 0,0,0);
      }
    }
    if (!last){
      asm volatile("s_waitcnt vmcnt(0)" ::: "memory");
      #pragma unroll
      for (int j=0;j<8;j++){
        Vt[cur^1][(8*w+j)*64    + (lane ^ (8*j))] = (u16)v0[j];
        Vt[cur^1][(32+8*w+j)*64 + (lane ^ (8*j))] = (u16)v1[j];
      }
      __syncthreads();
      cur ^= 1;
    }
  }
  // ---- finalize: Y = (accA + g*accB)/l ----
  float inv = 1.0f / l_r;
  float gq = Gate[qgrow*H_DIM + h];
  #pragma unroll
  for (int dn=0;dn<4;dn++){
    s16x4 o;
    #pragma unroll
    for (int r=0;r<4;r++) o[r] = (short)f2b((accA[dn][r] + gq*accB[dn][r])*inv);
    *(s16x4*)(Yb + qgrow*C_DIM + h*D_DIM + dn*16 + 4*g) = o;
  }
}

extern "C" void kernel_launch(void* const* d_in, const int* in_sizes, int n_in,
                              void* d_out, int out_size, void* d_ws, size_t ws_size,
                              hipStream_t stream)
{
  (void)in_sizes; (void)n_in; (void)out_size;
  const float* x  = (const float*)d_in[0];
  const float* fm = (const float*)d_in[1];
  const float* rm = (const float*)d_in[2];
  const float* Wq = (const float*)d_in[3];
  const float* Wk = (const float*)d_in[4];
  const float* Wv = (const float*)d_in[5];
  const float* Wo = (const float*)d_in[6];
  const float* gW = (const float*)d_in[7];
  const float* gb = (const float*)d_in[8];
  float* out = (float*)d_out;

  char* p = (char*)d_ws;
  u16* kvx  = (u16*)p;  p += (long)B_DIM*S_DIM*C_DIM*2;
  u16* qb   = (u16*)p;  p += (long)B_DIM*T_DIM*C_DIM*2;
  u16* kvb  = (u16*)p;  p += (long)B_DIM*S_DIM*KV_STRIDE*2;
  u16* yb   = (u16*)p;  p += (long)B_DIM*T_DIM*C_DIM*2;
  u16* WqT  = (u16*)p;  p += (long)C_DIM*C_DIM*2;
  u16* WkvT = (u16*)p;  p += (long)2*C_DIM*C_DIM*2;
  u16* WoT  = (u16*)p;  p += (long)C_DIM*C_DIM*2;
  float* Gate = (float*)p; p += (long)B_DIM*T_DIM*H_DIM*4;
  float* Part = (float*)p; p += (long)B_DIM*T_DIM*4;
  if ((size_t)(p - (char*)d_ws) > ws_size) return;

  prep_cast_kernel<<<(B_DIM*S_DIM*C_DIM/8)/256, 256, 0, stream>>>(x, fm, rm, kvx);
  transpose_w_kernel<<<(C_DIM*C_DIM/8)/256, 256, 0, stream>>>(Wq, WqT);
  transpose_w_kernel<<<(C_DIM*C_DIM/8)/256, 256, 0, stream>>>(Wk, WkvT);
  transpose_w_kernel<<<(C_DIM*C_DIM/8)/256, 256, 0, stream>>>(Wv, WkvT + (long)C_DIM*C_DIM);
  transpose_w_kernel<<<(C_DIM*C_DIM/8)/256, 256, 0, stream>>>(Wo, WoT);

  // q = x@Wq
  gemm_bt_kernel<<<dim3(C_DIM/128, (B_DIM*T_DIM)/128), 256, 0, stream>>>(kvx, WqT, qb, nullptr,
      C_DIM, C_DIM, T_DIM, S_DIM);
  // [k|v] = kvx@[Wk|Wv]  (N=2048)
  gemm_bt_kernel<<<dim3(KV_STRIDE/128, (B_DIM*S_DIM)/128), 256, 0, stream>>>(kvx, WkvT, kvb, nullptr,
      KV_STRIDE, C_DIM, B_DIM*S_DIM, B_DIM*S_DIM);

  gate_kernel<<<(B_DIM*T_DIM)/4, 256, 0, stream>>>(qb, gW, gb, Gate, Part);
  loss_kernel<<<1, 256, 0, stream>>>(Part, out);

  attn_kernel<<<B_DIM*H_DIM*(T_DIM/64), 256, 0, stream>>>(qb, kvb, Gate, yb);

  // out = Y@Wo (f32 into d_out)
  gemm_bt_kernel<<<dim3(C_DIM/128, (B_DIM*T_DIM)/128), 256, 0, stream>>>(yb, WoT, nullptr, out,
      C_DIM, C_DIM, B_DIM*T_DIM, B_DIM*T_DIM);
}